// Round 6
// baseline (220.219 us; speedup 1.0000x reference)
//
#include <hip/hip_runtime.h>

#define HW 4096
#define NCH 256
#define DIM 128
#define NPROTO 512

typedef __attribute__((ext_vector_type(4))) float f32x4;
typedef __attribute__((ext_vector_type(8))) short s16x8;

__device__ __forceinline__ unsigned short f2bf(float f) {
  union { float f; unsigned u; } v; v.f = f;
  unsigned r = v.u + 0x7fffu + ((v.u >> 16) & 1u);
  return (unsigned short)(r >> 16);
}

// ---------------------------------------------------------------------------
// prep: P -> bf16 chunked Pr[ch][512][32] (+pn2); W -> bf16 row-major [128][256]
// ---------------------------------------------------------------------------
__global__ __launch_bounds__(256) void prep_kernel(const float* __restrict__ P,
                                                   const float* __restrict__ Wm,
                                                   unsigned short* __restrict__ Pr,
                                                   unsigned short* __restrict__ Wbf,
                                                   float* __restrict__ pn2) {
  const int tid = threadIdx.x;
  const int b = blockIdx.x;
  if (b < 8) {
    const int n  = b * 64 + (tid >> 2);
    const int qt = tid & 3;  // d-chunk 32*qt..
    const float* row = P + n * DIM + qt * 32;
    unsigned short* dst = Pr + ((size_t)qt * NPROTO + n) * 32;
    float ssq = 0.f;
#pragma unroll
    for (int u = 0; u < 8; ++u) {
      f32x4 v = *(const f32x4*)(row + 4 * u);
      ssq += v.x * v.x + v.y * v.y + v.z * v.z + v.w * v.w;
      dst[4 * u + 0] = f2bf(v.x);
      dst[4 * u + 1] = f2bf(v.y);
      dst[4 * u + 2] = f2bf(v.z);
      dst[4 * u + 3] = f2bf(v.w);
    }
    ssq += __shfl_xor(ssq, 1);
    ssq += __shfl_xor(ssq, 2);
    if (qt == 0) pn2[n] = ssq;
  } else {
    const int idx = ((b - 8) * 256 + tid) * 16;  // 8*256*16 = 32768 = 128*256
#pragma unroll
    for (int u = 0; u < 4; ++u) {
      f32x4 v = *(const f32x4*)(Wm + idx + 4 * u);
      unsigned short* d = Wbf + idx + 4 * u;
      d[0] = f2bf(v.x); d[1] = f2bf(v.y); d[2] = f2bf(v.z); d[3] = f2bf(v.w);
    }
  }
}

// ---------------------------------------------------------------------------
// fused v3 (deep-prefetch): 32 px x 512 protos per block, 512 thr, 2048 blocks.
// All waits are compiler reg-dep waits (no manual vmcnt counting):
//   - W held as B-FRAGMENTS IN REGISTERS (wave w owns d-slice 16w..16w+16;
//     8 K-frags = 32 VGPR), loaded once from L2 at block start. No W LDS.
//   - ALL 4 K-steps of x prefetched into regs at block start (stager waves,
//     32 VGPR); pack of step it drains a load issued ~4 steps earlier.
//   - ONE barrier per K-iter (x_b dbuf: iter it+2's pack is fenced from
//     iter it's readers by iter it+1's barrier). Raw s_barrier + lgkm only.
//   - Phase 2: bq double-buffered regs; chunks 0+1 in flight across the
//     phase-2 barrier; no sched_barrier.
// Phase 1.5 swizzled q_s, exp2 softmax, direct f32x4 stores: proven.
// LDS 18688 B; VGPR ~90 -> __launch_bounds__(512,4).
// ---------------------------------------------------------------------------
__global__ __launch_bounds__(512, 4) void fused_kernel(
    const float* __restrict__ x, const unsigned short* __restrict__ Wbf,
    const float* __restrict__ bias, const unsigned short* __restrict__ Pr,
    const float* __restrict__ pn2, const float* __restrict__ gptr,
    float* __restrict__ out) {
  __shared__ __align__(16) char smem[18688];
  unsigned short* q_s = (unsigned short*)smem;  // [32][128] swizzled (8192)
  char* x_b = smem + 8192;                      // dbuf: 2 x (32 rows x 144B)
  float* red  = (float*)(smem + 17408);         // [8][32]
  float* rmx  = (float*)(smem + 18432);         // [32]
  float* rinv = (float*)(smem + 18560);         // [32]

  const int tid  = threadIdx.x;
  const int p0   = blockIdx.x * 32;
  const int nimg = p0 >> 12;
  const int hw0  = p0 & 4095;
  const int wave = tid >> 6, lane = tid & 63;
  const int l15 = lane & 15, l4 = lane >> 4;

  // ---- prologue: W fragments -> regs (oldest in VMEM stream, drained by
  //      the x-pack's reg-dep wait for free), then deep x prefetch ----
  const int dloc = 16 * wave + l15;  // this wave's d column for l15
  s16x8 wf[8];
  {
    const unsigned short* wrow = Wbf + (size_t)dloc * NCH + 8 * l4;
#pragma unroll
    for (int k = 0; k < 8; ++k) wf[k] = *(const s16x8*)(wrow + 32 * k);
  }

  const float* xb = x + (size_t)nimg * NCH * HW + hw0;
  const int f  = tid & 7;   // px quad: pixels 4f..4f+3
  const int cp = tid >> 3;  // channel pair 2cp,2cp+1 (stagers: tid<256)
  f32x4 xv[4][2];
  if (tid < 256) {
#pragma unroll
    for (int it = 0; it < 4; ++it) {
      xv[it][0] = *(const f32x4*)(xb + (size_t)(64 * it + 2 * cp + 0) * HW + 4 * f);
      xv[it][1] = *(const f32x4*)(xb + (size_t)(64 * it + 2 * cp + 1) * HW + 4 * f);
    }
  }
  const float bv = bias[dloc];

  // ---------------- phase 1: q = x W^T ----------------
  f32x4 acc1[2];
#pragma unroll
  for (int i = 0; i < 2; ++i)
#pragma unroll
    for (int r = 0; r < 4; ++r) acc1[i][r] = 0.f;

#pragma unroll
  for (int it = 0; it < 4; ++it) {
    char* xbuf = x_b + (it & 1) * 4608;
    if (tid < 256) {  // pack x(it): compiler waits exactly the xv[it] loads
#pragma unroll
      for (int s = 0; s < 4; ++s) {
        const int row = 4 * f + s;
        unsigned pk = (unsigned)f2bf(xv[it][0][s]) | ((unsigned)f2bf(xv[it][1][s]) << 16);
        *(unsigned*)(xbuf + row * 144 + ((4 * cp) ^ (((row >> 2) & 7) << 4))) = pk;
      }
    }
    asm volatile("s_waitcnt lgkmcnt(0)" ::: "memory");
    __builtin_amdgcn_s_barrier();
#pragma unroll
    for (int kc = 0; kc < 64; kc += 32) {
      const int ub = (kc >> 3) + l4;  // 16B unit 0..7
      s16x8 a[2];
#pragma unroll
      for (int i = 0; i < 2; ++i) {
        const int row = 16 * i + l15;
        a[i] = *(const s16x8*)(xbuf + row * 144 + 16 * (ub ^ ((row >> 2) & 7)));
      }
#pragma unroll
      for (int i = 0; i < 2; ++i)
        acc1[i] = __builtin_amdgcn_mfma_f32_16x16x32_bf16(a[i], wf[2 * it + (kc >> 5)],
                                                          acc1[i], 0, 0, 0);
    }
    // no trailing barrier: iter it+2's pack (same buf) is fenced from this
    // iter's readers by iter it+1's top barrier (program-order proof in notes)
  }

  // ---------------- phase 1.5: q + bias -> q_s (swizzled bf16) ----------------
  // C/D layout: col = l15 (d = dloc), row = 4*l4 + r (px)
  {
    const int u = dloc >> 3, d7 = dloc & 7;
#pragma unroll
    for (int i = 0; i < 2; ++i) {
      const int pxb = 16 * i + 4 * l4;
#pragma unroll
      for (int r = 0; r < 4; ++r) {
        const int px = pxb + r;
        q_s[px * 128 + ((u ^ (px & 7)) << 3) + d7] = f2bf(acc1[i][r] + bv);
      }
    }
  }

  // ---------------- phase 2: attn, bq double-buffered from global ----------------
  f32x4 acc[2][4];
#pragma unroll
  for (int i = 0; i < 2; ++i)
#pragma unroll
    for (int j = 0; j < 4; ++j)
#pragma unroll
      for (int r = 0; r < 4; ++r) acc[i][j][r] = 0.f;

  s16x8 bqA[4], bqB[4];
#pragma unroll
  for (int j = 0; j < 4; ++j)
    bqA[j] = *(const s16x8*)(Pr + (size_t)(0 * NPROTO + 64 * wave + 16 * j + l15) * 32 + 8 * l4);
#pragma unroll
  for (int j = 0; j < 4; ++j)
    bqB[j] = *(const s16x8*)(Pr + (size_t)(1 * NPROTO + 64 * wave + 16 * j + l15) * 32 + 8 * l4);
  asm volatile("s_waitcnt lgkmcnt(0)" ::: "memory");
  __builtin_amdgcn_s_barrier();  // q_s visible; bq loads stay in flight

#define DO_CHUNK(CH, BQ)                                                        \
  {                                                                             \
    s16x8 afr[2];                                                               \
    _Pragma("unroll") for (int i = 0; i < 2; ++i) {                             \
      const int px = 16 * i + l15;                                              \
      afr[i] = *(const s16x8*)&q_s[px * 128 + (((4 * (CH) + l4) ^ (px & 7)) << 3)]; \
    }                                                                           \
    _Pragma("unroll") for (int j = 0; j < 4; ++j)                               \
      _Pragma("unroll") for (int i = 0; i < 2; ++i)                             \
        acc[i][j] = __builtin_amdgcn_mfma_f32_16x16x32_bf16(afr[i], BQ[j], acc[i][j], 0, 0, 0); \
  }

  DO_CHUNK(0, bqA);
#pragma unroll
  for (int j = 0; j < 4; ++j)  // refill A with chunk 2 (WAR on regs only)
    bqA[j] = *(const s16x8*)(Pr + (size_t)(2 * NPROTO + 64 * wave + 16 * j + l15) * 32 + 8 * l4);
  DO_CHUNK(1, bqB);
#pragma unroll
  for (int j = 0; j < 4; ++j)  // refill B with chunk 3
    bqB[j] = *(const s16x8*)(Pr + (size_t)(3 * NPROTO + 64 * wave + 16 * j + l15) * 32 + 8 * l4);
  DO_CHUNK(2, bqA);
  DO_CHUNK(3, bqB);
#undef DO_CHUNK

  // softmax over 512 protos (exp2 domain; qn2 row-constant cancels)
  const float g2  = fabsf(gptr[0]) * 1.44269504088896340736f;
  const float tg2 = 2.f * g2;
  float cj[4];
#pragma unroll
  for (int j = 0; j < 4; ++j) cj[j] = g2 * pn2[64 * wave + 16 * j + l15];

#pragma unroll
  for (int i = 0; i < 2; ++i)
#pragma unroll
    for (int r = 0; r < 4; ++r) {
      float m = -1e30f;
#pragma unroll
      for (int j = 0; j < 4; ++j) {
        float lv = fmaf(acc[i][j][r], tg2, -cj[j]);
        acc[i][j][r] = lv;
        m = fmaxf(m, lv);
      }
#pragma unroll
      for (int s = 1; s < 16; s <<= 1) m = fmaxf(m, __shfl_xor(m, s));
      if (l15 == 0) red[wave * 32 + 16 * i + 4 * l4 + r] = m;
    }
  __syncthreads();
  if (tid < 32) {
    float M = red[tid];
#pragma unroll
    for (int w = 1; w < 8; ++w) M = fmaxf(M, red[w * 32 + tid]);
    rmx[tid] = M;
  }
  __syncthreads();

#pragma unroll
  for (int i = 0; i < 2; ++i) {
    const f32x4 Mi = *(const f32x4*)&rmx[16 * i + 4 * l4];
#pragma unroll
    for (int r = 0; r < 4; ++r) {
      float s = 0.f;
#pragma unroll
      for (int j = 0; j < 4; ++j) {
        float e = exp2f(acc[i][j][r] - Mi[r]);
        acc[i][j][r] = e;
        s += e;
      }
#pragma unroll
      for (int t = 1; t < 16; t <<= 1) s += __shfl_xor(s, t);
      if (l15 == 0) red[wave * 32 + 16 * i + 4 * l4 + r] = s;
    }
  }
  __syncthreads();
  if (tid < 32) {
    float S = 0.f;
#pragma unroll
    for (int w = 0; w < 8; ++w) S += red[w * 32 + tid];
    rinv[tid] = 1.f / S;
  }
  __syncthreads();

  // direct stores: f32x4 over r = 4 consecutive px
  float* ob = out + (size_t)nimg * NPROTO * HW + hw0;
#pragma unroll
  for (int i = 0; i < 2; ++i) {
    const f32x4 iv = *(const f32x4*)&rinv[16 * i + 4 * l4];
    const int px = 16 * i + 4 * l4;
#pragma unroll
    for (int j = 0; j < 4; ++j) {
      const int k = 64 * wave + 16 * j + l15;
      f32x4 o = acc[i][j] * iv;
      *(f32x4*)(ob + (size_t)k * HW + px) = o;
    }
  }
}

extern "C" void kernel_launch(void* const* d_in, const int* in_sizes, int n_in,
                              void* d_out, int out_size, void* d_ws, size_t ws_size,
                              hipStream_t stream) {
  const float* x     = (const float*)d_in[0];
  const float* Wm    = (const float*)d_in[1];
  const float* bias  = (const float*)d_in[2];
  const float* prot  = (const float*)d_in[3];
  const float* gamma = (const float*)d_in[4];
  float* out = (float*)d_out;

  // workspace: Pr chunked bf16 (128 KiB) | pn2 (2 KiB) | W bf16 (64 KiB)
  unsigned short* Pr_w  = (unsigned short*)d_ws;
  float*          pn2_w = (float*)((char*)d_ws + 131072);
  unsigned short* W_ws  = (unsigned short*)((char*)d_ws + 131072 + 2048);

  prep_kernel<<<16, 256, 0, stream>>>(prot, Wm, Pr_w, W_ws, pn2_w);
  fused_kernel<<<2048, 512, 0, stream>>>(x, W_ws, bias, Pr_w, pn2_w, gamma, out);
}